// Round 1
// baseline (59.460 us; speedup 1.0000x reference)
//
#include <hip/hip_runtime.h>

// IMMLoss: B=32 groups, M=4 rows, D=196608 features, f32.
// loss = mean_b( wtout[b] * (mean K(st,st) + mean K(sr,sr) - 2*mean K(st,sr)) )
// K(x,y)_ij = exp(clip(-w[b]*sqrt(max(|x_i-y_j|^2,1e-12))/D, -1e6, 0))
// |x_i-y_j|^2 via gram expansion: xn_i + yn_j - 2*xy_ij.

constexpr int NB = 32;       // groups
constexpr int MM = 4;        // rows per group
constexpr int DD = 196608;   // feature dim
constexpr int D4 = DD / 4;   // 49152 float4 per row
constexpr int BPG = 32;      // blocks per group
constexpr int NTHREADS = 256;
constexpr int CHUNK4 = D4 / BPG;   // 1536 float4 per block per row (6 iters/thread)
constexpr int NACC = 36;           // 10 ss-tri + 10 rr-tri + 16 cross

__global__ __launch_bounds__(NTHREADS) void mmd_partial_kernel(
    const float* __restrict__ st, const float* __restrict__ sr,
    float* __restrict__ partial)
{
    const int b   = blockIdx.x / BPG;
    const int blk = blockIdx.x % BPG;
    const float4* __restrict__ stb =
        reinterpret_cast<const float4*>(st) + (size_t)b * MM * D4;
    const float4* __restrict__ srb =
        reinterpret_cast<const float4*>(sr) + (size_t)b * MM * D4;
    const int base = blk * CHUNK4;

    float acc[NACC];
#pragma unroll
    for (int k = 0; k < NACC; ++k) acc[k] = 0.0f;

#pragma unroll 2
    for (int it = threadIdx.x; it < CHUNK4; it += NTHREADS) {
        const int idx = base + it;
        float4 x[MM], y[MM];
#pragma unroll
        for (int i = 0; i < MM; ++i) x[i] = stb[(size_t)i * D4 + idx];
#pragma unroll
        for (int i = 0; i < MM; ++i) y[i] = srb[(size_t)i * D4 + idx];

        int k = 0;
#pragma unroll
        for (int i = 0; i < MM; ++i) {
#pragma unroll
            for (int j = i; j < MM; ++j) {
                acc[k] += x[i].x * x[j].x + x[i].y * x[j].y +
                          x[i].z * x[j].z + x[i].w * x[j].w;
                ++k;
            }
        }
#pragma unroll
        for (int i = 0; i < MM; ++i) {
#pragma unroll
            for (int j = i; j < MM; ++j) {
                acc[k] += y[i].x * y[j].x + y[i].y * y[j].y +
                          y[i].z * y[j].z + y[i].w * y[j].w;
                ++k;
            }
        }
#pragma unroll
        for (int i = 0; i < MM; ++i) {
#pragma unroll
            for (int j = 0; j < MM; ++j) {
                acc[k] += x[i].x * y[j].x + x[i].y * y[j].y +
                          x[i].z * y[j].z + x[i].w * y[j].w;
                ++k;
            }
        }
    }

    // Wave (64-lane) butterfly reduce, then cross-wave via LDS.
#pragma unroll
    for (int k = 0; k < NACC; ++k) {
        float v = acc[k];
        for (int off = 32; off > 0; off >>= 1) v += __shfl_down(v, off, 64);
        acc[k] = v;
    }

    __shared__ float red[NTHREADS / 64][NACC];
    const int wave = threadIdx.x >> 6;
    const int lane = threadIdx.x & 63;
    if (lane == 0) {
#pragma unroll
        for (int k = 0; k < NACC; ++k) red[wave][k] = acc[k];
    }
    __syncthreads();
    if (threadIdx.x < NACC) {
        const int k = threadIdx.x;
        float s = red[0][k] + red[1][k] + red[2][k] + red[3][k];
        partial[(size_t)blockIdx.x * NACC + k] = s;
    }
}

__global__ __launch_bounds__(64) void mmd_final_kernel(
    const float* __restrict__ partial, const float* __restrict__ wt,
    const float* __restrict__ wtout, float* __restrict__ out)
{
    __shared__ float lds[NB];
    const int b = threadIdx.x;
    if (b < NB) {
        float a[NACC];
#pragma unroll
        for (int k = 0; k < NACC; ++k) a[k] = 0.0f;
        for (int blk = 0; blk < BPG; ++blk) {
            const float* p = partial + ((size_t)b * BPG + blk) * NACC;
#pragma unroll
            for (int k = 0; k < NACC; ++k) a[k] += p[k];
        }

        float ss[MM][MM], rr[MM][MM], sg[MM][MM];
        {
            int k = 0;
            for (int i = 0; i < MM; ++i)
                for (int j = i; j < MM; ++j) { ss[i][j] = a[k]; ss[j][i] = a[k]; ++k; }
            for (int i = 0; i < MM; ++i)
                for (int j = i; j < MM; ++j) { rr[i][j] = a[k]; rr[j][i] = a[k]; ++k; }
            for (int i = 0; i < MM; ++i)
                for (int j = 0; j < MM; ++j) { sg[i][j] = a[k]; ++k; }
        }

        const float w    = wt[b];
        const float invD = 1.0f / (float)DD;  // sigma = 1
        auto kv = [&](float d2) -> float {
            d2 = fmaxf(d2, 1e-12f);
            float dist = sqrtf(d2) * invD;
            float e = -dist * w;
            e = fminf(fmaxf(e, -1e6f), 0.0f);
            return expf(e);
        };

        float mss = 0.0f, mrr = 0.0f, msr = 0.0f;
        for (int i = 0; i < MM; ++i) {
            for (int j = 0; j < MM; ++j) {
                mss += kv(ss[i][i] + ss[j][j] - 2.0f * ss[i][j]);
                mrr += kv(rr[i][i] + rr[j][j] - 2.0f * rr[i][j]);
                msr += kv(ss[i][i] + rr[j][j] - 2.0f * sg[i][j]);
            }
        }
        const float inv16 = 1.0f / 16.0f;
        float loss_raw = mss * inv16 + mrr * inv16 - 2.0f * (msr * inv16);
        lds[b] = wtout[b] * loss_raw;
    }
    __syncthreads();
    if (threadIdx.x == 0) {
        float s = 0.0f;
        for (int i = 0; i < NB; ++i) s += lds[i];
        out[0] = s / (float)NB;
    }
}

extern "C" void kernel_launch(void* const* d_in, const int* in_sizes, int n_in,
                              void* d_out, int out_size, void* d_ws, size_t ws_size,
                              hipStream_t stream) {
    const float* f_st  = (const float*)d_in[0];
    const float* f_sr  = (const float*)d_in[1];
    const float* wt    = (const float*)d_in[2];
    const float* wtout = (const float*)d_in[3];
    float* out     = (float*)d_out;
    float* partial = (float*)d_ws;   // NB*BPG*NACC floats = 147456 B

    mmd_partial_kernel<<<NB * BPG, NTHREADS, 0, stream>>>(f_st, f_sr, partial);
    mmd_final_kernel<<<1, 64, 0, stream>>>(partial, wt, wtout, out);
}